// Round 8
// baseline (7420.628 us; speedup 1.0000x reference)
//
#include <hip/hip_runtime.h>
#include <math.h>

#define SLOPE 0.01f

typedef __attribute__((ext_vector_type(8))) short bf16x8;
typedef __attribute__((ext_vector_type(4))) float f32x4;
typedef unsigned short ushort_t;

__device__ __forceinline__ float lrelu(float x) {
    return x > 0.f ? x : SLOPE * x;
}

__device__ __forceinline__ unsigned short f2bf(float f) {
    unsigned int u = __float_as_uint(f);
    u += 0x7fffu + ((u >> 16) & 1u);
    return (unsigned short)(u >> 16);
}

__device__ __forceinline__ float bf2f(unsigned short u) {
    return __uint_as_float((unsigned int)u << 16);
}

// ---------------------------------------------------------------------------
// f32 -> bf16 conversion, 4 elems/thread
// ---------------------------------------------------------------------------
__global__ void cvt_bf16_kernel(const float* __restrict__ src,
                                unsigned short* __restrict__ dst, int n4) {
    int i = blockIdx.x * blockDim.x + threadIdx.x;
    if (i >= n4) return;
    float4 v = ((const float4*)src)[i];
    uint2 o;
    o.x = (unsigned)f2bf(v.x) | ((unsigned)f2bf(v.y) << 16);
    o.y = (unsigned)f2bf(v.z) | ((unsigned)f2bf(v.w) << 16);
    ((uint2*)dst)[i] = o;
}

// ---------------------------------------------------------------------------
// Fused conv1(5x5)+conv2(3x3)+conv3(3x3), all 4->4 ch, SAME, bias+LeakyReLU.
// Grid (2048 images, 6 row-tiles of 14). Intermediates live in LDS as f32.
// Halo rows/cols OUTSIDE the image are zeroed (true SAME-padding semantics);
// halo rows inside the image are computed redundantly.
// ---------------------------------------------------------------------------
__device__ __forceinline__ void conv_unit5(const float* __restrict__ in0, int chS,
                                           const float* __restrict__ wle,
                                           const float* __restrict__ bs,
                                           float acc[4][4]) {
    #pragma unroll
    for (int co = 0; co < 4; ++co)
        #pragma unroll
        for (int dw = 0; dw < 4; ++dw) acc[co][dw] = bs[co];
    #pragma unroll
    for (int ci = 0; ci < 4; ++ci) {
        #pragma unroll
        for (int kh = 0; kh < 5; ++kh) {
            const float* p = in0 + ci * chS + kh * 88;
            float4 v0 = *(const float4*)p;
            float4 v1 = *(const float4*)(p + 4);
            float vals[8] = {v0.x, v0.y, v0.z, v0.w, v1.x, v1.y, v1.z, v1.w};
            const float* wrow = wle + (ci * 5 + kh) * 24;  // [co][6]
            #pragma unroll
            for (int co = 0; co < 4; ++co) {
                #pragma unroll
                for (int kw = 0; kw < 5; ++kw) {
                    float wv = wrow[co * 6 + kw];
                    #pragma unroll
                    for (int dw = 0; dw < 4; ++dw)
                        acc[co][dw] += vals[kw + dw] * wv;
                }
            }
        }
    }
}

__device__ __forceinline__ void conv_unit3(const float* __restrict__ in0, int chS,
                                           const float* __restrict__ wle,
                                           const float* __restrict__ bs,
                                           float acc[4][4]) {
    #pragma unroll
    for (int co = 0; co < 4; ++co)
        #pragma unroll
        for (int dw = 0; dw < 4; ++dw) acc[co][dw] = bs[co];
    #pragma unroll
    for (int ci = 0; ci < 4; ++ci) {
        #pragma unroll
        for (int kh = 0; kh < 3; ++kh) {
            const float* p = in0 + ci * chS + kh * 88;
            float4 v0 = *(const float4*)p;
            float2 v1 = *(const float2*)(p + 4);
            float vals[6] = {v0.x, v0.y, v0.z, v0.w, v1.x, v1.y};
            const float* wrow = wle + (ci * 3 + kh) * 16;  // [co][4]
            #pragma unroll
            for (int co = 0; co < 4; ++co) {
                #pragma unroll
                for (int kw = 0; kw < 3; ++kw) {
                    float wv = wrow[co * 4 + kw];
                    #pragma unroll
                    for (int dw = 0; dw < 4; ++dw)
                        acc[co][dw] += vals[kw + dw] * wv;
                }
            }
        }
    }
}

__global__ __launch_bounds__(256) void conv_fused_kernel(
        const float* __restrict__ x,
        const float* __restrict__ w1, const float* __restrict__ b1,
        const float* __restrict__ w2, const float* __restrict__ b2,
        const float* __restrict__ w3, const float* __restrict__ b3,
        unsigned short* __restrict__ out) {
    // uni: x strip [4][22][88] f32, later aliased by conv2 out [4][16][88]
    __shared__ float uni[4 * 22 * 88];
    __shared__ float b1s[4 * 18 * 88];
    __shared__ float w1le[480];   // [ci][kh=5][co][6]
    __shared__ float w2le[192];   // [ci][kh=3][co][4]
    __shared__ float w3le[192];
    __shared__ float bias_s[12];

    #define XS(ci, r, c)  uni[((ci) * 22 + (r)) * 88 + (c)]   // col c <-> global c-2
    #define B2S(ci, r, c) uni[((ci) * 16 + (r)) * 88 + (c)]   // col c <-> global c-1
    #define B1S(ci, r, c) b1s[((ci) * 18 + (r)) * 88 + (c)]   // col c <-> global c-1

    int tid = threadIdx.x;
    int n = blockIdx.x;
    int r0 = blockIdx.y * 14;
    const size_t imgOff = (size_t)n * (4 * 84 * 84);

    // --- P0: weights + biases + x strip (rows r0-4 .. r0+17, zero halo) ---
    for (int i = tid; i < 400; i += 256) {
        int kw = i % 5; int t2 = i / 5;
        int kh = t2 % 5; int t3 = t2 / 5;
        int ci = t3 & 3; int co = t3 >> 2;
        w1le[(ci * 5 + kh) * 24 + co * 6 + kw] = w1[i];
    }
    if (tid < 144) {
        int i = tid;
        int kw = i % 3; int t2 = i / 3;
        int kh = t2 % 3; int t3 = t2 / 3;
        int ci = t3 & 3; int co = t3 >> 2;
        w2le[(ci * 3 + kh) * 16 + co * 4 + kw] = w2[i];
        w3le[(ci * 3 + kh) * 16 + co * 4 + kw] = w3[i];
    }
    if (tid < 4) {
        bias_s[tid] = b1[tid];
        bias_s[4 + tid] = b2[tid];
        bias_s[8 + tid] = b3[tid];
    }
    for (int i = tid; i < 4 * 22 * 88; i += 256) {
        int c = i % 88; int t2 = i / 88;
        int r = t2 % 22; int ci = t2 / 22;
        int gr = r0 - 4 + r;
        int gc = c - 2;
        float v = 0.f;
        if ((unsigned)gr < 84u && (unsigned)gc < 84u)
            v = x[imgOff + ((size_t)ci * 84 + gr) * 84 + gc];
        uni[i] = v;
    }
    __syncthreads();

    // --- P1: conv1 -> B1 (18 rows; zero rows outside image; halo cols 0/85) ---
    for (int u = tid; u < 18 * 21; u += 256) {
        int r1 = u / 21, cg = u % 21;
        int g1 = r0 - 2 + r1;
        float acc[4][4];
        conv_unit5(&XS(0, r1, cg * 4), 22 * 88, w1le, bias_s, acc);
        bool valid = (unsigned)g1 < 84u;
        #pragma unroll
        for (int co = 0; co < 4; ++co)
            #pragma unroll
            for (int dw = 0; dw < 4; ++dw)
                B1S(co, r1, 1 + cg * 4 + dw) = valid ? lrelu(acc[co][dw]) : 0.f;
    }
    if (tid < 144) {   // zero B1 halo cols 0 and 85 (4co x 18r x 2)
        int co = tid / 36; int rr = (tid % 36) >> 1; int cc = (tid & 1) ? 85 : 0;
        B1S(co, rr, cc) = 0.f;
    }
    __syncthreads();

    // --- P2: conv2 -> B2 (16 rows, aliases x strip; zero invalid rows/halo) ---
    if (tid < 128) {   // zero B2 halo cols 0 and 85 (4co x 16r x 2)
        int co = tid / 32; int rr = (tid % 32) >> 1; int cc = (tid & 1) ? 85 : 0;
        B2S(co, rr, cc) = 0.f;
    }
    for (int u = tid; u < 16 * 21; u += 256) {
        int r2 = u / 21, cg = u % 21;
        int g2 = r0 - 1 + r2;
        float acc[4][4];
        conv_unit3(&B1S(0, r2, cg * 4), 18 * 88, w2le, bias_s + 4, acc);
        bool valid = (unsigned)g2 < 84u;
        #pragma unroll
        for (int co = 0; co < 4; ++co)
            #pragma unroll
            for (int dw = 0; dw < 4; ++dw)
                B2S(co, r2, 1 + cg * 4 + dw) = valid ? lrelu(acc[co][dw]) : 0.f;
    }
    __syncthreads();

    // --- P3: conv3 -> global bf16 (14 output rows) ---
    for (int u = tid; u < 14 * 21; u += 256) {
        int ro = u / 21, cg = u % 21;
        float acc[4][4];
        conv_unit3(&B2S(0, ro, cg * 4), 16 * 88, w3le, bias_s + 8, acc);
        int go = r0 + ro;
        #pragma unroll
        for (int co = 0; co < 4; ++co) {
            float o0 = lrelu(acc[co][0]);
            float o1 = lrelu(acc[co][1]);
            float o2 = lrelu(acc[co][2]);
            float o3 = lrelu(acc[co][3]);
            uint2 p;
            p.x = (unsigned)f2bf(o0) | ((unsigned)f2bf(o1) << 16);
            p.y = (unsigned)f2bf(o2) | ((unsigned)f2bf(o3) << 16);
            *(uint2*)(out + imgOff + ((size_t)co * 84 + go) * 84 + cg * 4) = p;
        }
    }
    #undef XS
    #undef B2S
    #undef B1S
}

// ---------------------------------------------------------------------------
// bf16 MFMA GEMM (NT) with epilogue (fc2, heads). (unchanged)
// ---------------------------------------------------------------------------
template<bool DO_LRELU, bool BIAS2, bool OUTBF>
__global__ void gemm_bf16_kernel(const unsigned short* __restrict__ A,
                                 const unsigned short* __restrict__ B,
                                 const float* __restrict__ bias,
                                 const float* __restrict__ bias2,
                                 void* __restrict__ Cout,
                                 int M, int N, int K) {
    __shared__ unsigned short As[64][40];
    __shared__ unsigned short Bs[64][40];
    int tid = threadIdx.x;
    int rowBase = blockIdx.y * 64;
    int colBase = blockIdx.x * 64;

    int wave = tid >> 6;
    int l    = tid & 63;
    int wr = wave >> 1, wc = wave & 1;
    int lane16 = l & 15;
    int kb = (l >> 4) * 8;

    int sr = tid >> 2;
    int sk = (tid & 3) << 3;
    const unsigned short* Ap = A + (size_t)(rowBase + sr) * K + sk;
    const unsigned short* Bp = B + (size_t)(colBase + sr) * K + sk;

    f32x4 acc[2][2] = {};

    for (int k0 = 0; k0 < K; k0 += 32) {
        float4 av = *(const float4*)(Ap + k0);
        float4 bv = *(const float4*)(Bp + k0);
        __syncthreads();
        *(float4*)(&As[sr][sk]) = av;
        *(float4*)(&Bs[sr][sk]) = bv;
        __syncthreads();
        bf16x8 a0 = *(const bf16x8*)(&As[wr * 32 + lane16][kb]);
        bf16x8 a1 = *(const bf16x8*)(&As[wr * 32 + 16 + lane16][kb]);
        bf16x8 b0 = *(const bf16x8*)(&Bs[wc * 32 + lane16][kb]);
        bf16x8 b1 = *(const bf16x8*)(&Bs[wc * 32 + 16 + lane16][kb]);
        acc[0][0] = __builtin_amdgcn_mfma_f32_16x16x32_bf16(a0, b0, acc[0][0], 0, 0, 0);
        acc[0][1] = __builtin_amdgcn_mfma_f32_16x16x32_bf16(a0, b1, acc[0][1], 0, 0, 0);
        acc[1][0] = __builtin_amdgcn_mfma_f32_16x16x32_bf16(a1, b0, acc[1][0], 0, 0, 0);
        acc[1][1] = __builtin_amdgcn_mfma_f32_16x16x32_bf16(a1, b1, acc[1][1], 0, 0, 0);
    }

    int crow0 = rowBase + wr * 32 + (l >> 4) * 4;
    int ccol0 = colBase + wc * 32 + lane16;
    float bsv[2];
    #pragma unroll
    for (int j = 0; j < 2; ++j) {
        bsv[j] = bias[ccol0 + j * 16];
        if (BIAS2) bsv[j] += bias2[ccol0 + j * 16];
    }
    #pragma unroll
    for (int i = 0; i < 2; ++i) {
        #pragma unroll
        for (int r = 0; r < 4; ++r) {
            int row = crow0 + i * 16 + r;
            #pragma unroll
            for (int j = 0; j < 2; ++j) {
                float v = acc[i][j][r] + bsv[j];
                if (DO_LRELU) v = lrelu(v);
                size_t off = (size_t)row * N + ccol0 + j * 16;
                if (OUTBF) ((unsigned short*)Cout)[off] = f2bf(v);
                else       ((float*)Cout)[off] = v;
            }
        }
    }
}

// ---------------------------------------------------------------------------
// Split-K bf16 MFMA GEMM: writes f32 partials. (unchanged)
// ---------------------------------------------------------------------------
__global__ void gemm_bf16_splitk_kernel(const unsigned short* __restrict__ A,
                                        const unsigned short* __restrict__ B,
                                        float* __restrict__ part,
                                        int M, int N, int K, int kChunk) {
    __shared__ unsigned short As[64][40];
    __shared__ unsigned short Bs[64][40];
    int tid = threadIdx.x;
    int rowBase = blockIdx.y * 64;
    int colBase = blockIdx.x * 64;
    int s = blockIdx.z;
    int kStart = s * kChunk;
    int kEnd = kStart + kChunk;

    int wave = tid >> 6;
    int l    = tid & 63;
    int wr = wave >> 1, wc = wave & 1;
    int lane16 = l & 15;
    int kb = (l >> 4) * 8;

    int sr = tid >> 2;
    int sk = (tid & 3) << 3;
    const unsigned short* Ap = A + (size_t)(rowBase + sr) * K + sk;
    const unsigned short* Bp = B + (size_t)(colBase + sr) * K + sk;

    f32x4 acc[2][2] = {};

    for (int k0 = kStart; k0 < kEnd; k0 += 32) {
        float4 av = *(const float4*)(Ap + k0);
        float4 bv = *(const float4*)(Bp + k0);
        __syncthreads();
        *(float4*)(&As[sr][sk]) = av;
        *(float4*)(&Bs[sr][sk]) = bv;
        __syncthreads();
        bf16x8 a0 = *(const bf16x8*)(&As[wr * 32 + lane16][kb]);
        bf16x8 a1 = *(const bf16x8*)(&As[wr * 32 + 16 + lane16][kb]);
        bf16x8 b0 = *(const bf16x8*)(&Bs[wc * 32 + lane16][kb]);
        bf16x8 b1 = *(const bf16x8*)(&Bs[wc * 32 + 16 + lane16][kb]);
        acc[0][0] = __builtin_amdgcn_mfma_f32_16x16x32_bf16(a0, b0, acc[0][0], 0, 0, 0);
        acc[0][1] = __builtin_amdgcn_mfma_f32_16x16x32_bf16(a0, b1, acc[0][1], 0, 0, 0);
        acc[1][0] = __builtin_amdgcn_mfma_f32_16x16x32_bf16(a1, b0, acc[1][0], 0, 0, 0);
        acc[1][1] = __builtin_amdgcn_mfma_f32_16x16x32_bf16(a1, b1, acc[1][1], 0, 0, 0);
    }

    float* Cp = part + (size_t)s * M * N;
    int crow0 = rowBase + wr * 32 + (l >> 4) * 4;
    int ccol0 = colBase + wc * 32 + lane16;
    #pragma unroll
    for (int i = 0; i < 2; ++i)
        #pragma unroll
        for (int r = 0; r < 4; ++r) {
            int row = crow0 + i * 16 + r;
            #pragma unroll
            for (int j = 0; j < 2; ++j)
                Cp[(size_t)row * N + ccol0 + j * 16] = acc[i][j][r];
        }
}

// ---------------------------------------------------------------------------
// Split-K reduce. (unchanged)
// ---------------------------------------------------------------------------
template<int S>
__global__ void splitk_reduce_kernel(const float* __restrict__ part,
                                     const float* __restrict__ bias,
                                     unsigned short* __restrict__ out,
                                     int MN, int N) {
    int i4 = blockIdx.x * blockDim.x + threadIdx.x;
    if (i4 * 4 >= MN) return;
    float4 acc = ((const float4*)part)[i4];
    #pragma unroll
    for (int s = 1; s < S; ++s) {
        float4 p = ((const float4*)(part + (size_t)s * MN))[i4];
        acc.x += p.x; acc.y += p.y; acc.z += p.z; acc.w += p.w;
    }
    int col4 = i4 % (N / 4);
    float4 bv = ((const float4*)bias)[col4];
    float o0 = lrelu(acc.x + bv.x);
    float o1 = lrelu(acc.y + bv.y);
    float o2 = lrelu(acc.z + bv.z);
    float o3 = lrelu(acc.w + bv.w);
    uint2 p;
    p.x = (unsigned)f2bf(o0) | ((unsigned)f2bf(o1) << 16);
    p.y = (unsigned)f2bf(o2) | ((unsigned)f2bf(o3) << 16);
    ((uint2*)out)[i4] = p;
}

// ---------------------------------------------------------------------------
// LSTM init: HA (bf16) = h0; zero barrier counter.
// ---------------------------------------------------------------------------
__global__ void lstm_init_kernel(const float* __restrict__ h0,
                                 unsigned short* __restrict__ HA,
                                 int* __restrict__ bar) {
    int i = blockIdx.x * blockDim.x + threadIdx.x;
    if (i < 16384) HA[i] = f2bf(h0[i]);
    if (i < 2) bar[i] = 0;
}

// ---------------------------------------------------------------------------
// Persistent LSTM scan with FUSED x-gate GEMM (gx kernel removed).
// 64 blocks x 256 threads (wave g = gate g). Per step:
//   stage h_{t-1} AND hfc2[t] slices into LDS (16 KB each)
//   wave g: hacc = Whh_g @ h^T, xacc = Wih_g @ hfc2^T  (W frags in VGPRs,
//           __launch_bounds__(256,1) gives the allocator room for 128 regs)
//   Gs[g] = xacc + m*hacc; pointwise adds (bih+bhh) and updates c,h.
// Barrier: R7-proven release-add / relaxed-spin / single acquire fence.
// ---------------------------------------------------------------------------
__global__ __launch_bounds__(256, 1) void lstm_scan_kernel(
        const unsigned short* __restrict__ whh_b,   // [2048][512] bf16
        const unsigned short* __restrict__ wih_b,   // [2048][512] bf16
        const float* __restrict__ bih,
        const float* __restrict__ bhh,
        const unsigned short* __restrict__ HA,      // [32][512] bf16
        const float* __restrict__ c0,               // [32][512] f32
        const unsigned short* __restrict__ hfc2,    // [2048][512] bf16
        const float* __restrict__ done,             // [2048] f32
        unsigned short* __restrict__ feat,          // [2048][512] bf16
        float* __restrict__ hN, float* __restrict__ cN,
        int* __restrict__ bar) {
    __shared__ float mds[2048];
    __shared__ float Gs[4][16][17];
    __shared__ unsigned short Hs[16][520];
    __shared__ unsigned short Xh[16][520];

    int tid = threadIdx.x;
    int jt = blockIdx.x >> 1;
    int bt = blockIdx.x & 1;

    for (int i = tid; i < 2048; i += 256) mds[i] = 1.0f - done[i];

    // MFMA identity (wave g computes gate g); W fragments -> registers
    int g = tid >> 6;
    int l = tid & 63;
    int lane16 = l & 15;
    int khi = l >> 4;
    const unsigned short* Wp =
        whh_b + ((size_t)g * 512 + jt * 16 + lane16) * 512 + khi * 8;
    const unsigned short* Wxp =
        wih_b + ((size_t)g * 512 + jt * 16 + lane16) * 512 + khi * 8;
    bf16x8 wreg[16], wxreg[16];
    #pragma unroll
    for (int kk = 0; kk < 16; ++kk) {
        wreg[kk]  = *(const bf16x8*)(Wp + kk * 32);
        wxreg[kk] = *(const bf16x8*)(Wxp + kk * 32);
    }

    // pointwise identity (thread owns (j,b))
    int jloc = tid & 15;
    int bloc = tid >> 4;
    int j = jt * 16 + jloc;
    int b = bt * 16 + bloc;
    float c_reg = c0[b * 512 + j];
    float bsv[4];
    #pragma unroll
    for (int gg = 0; gg < 4; ++gg)
        bsv[gg] = bih[gg * 512 + j] + bhh[gg * 512 + j];

    float mcol_base;   // per-lane column mask (set per step below)
    (void)mcol_base;

    __syncthreads();

    for (int t = 0; t < 64; ++t) {
        // --- stage h_{t-1} and hfc2[t] (bt-half: 16 rows x 512 bf16 each) ---
        const unsigned short* Hsrc =
            (t == 0 ? HA : feat + (size_t)(t - 1) * 16384) + bt * 8192;
        const unsigned short* Xsrc = hfc2 + (size_t)t * 16384 + bt * 8192;
        const float4* h4 = (const float4*)Hsrc;
        const float4* x4 = (const float4*)Xsrc;
        #pragma unroll
        for (int u0 = 0; u0 < 4; ++u0) {
            int u = tid + u0 * 256;
            float4 hv = h4[u];
            float4 xv = x4[u];
            int br = u >> 6;
            int ko = (u & 63) * 8;
            *(float4*)&Hs[br][ko] = hv;
            *(float4*)&Xh[br][ko] = xv;
        }
        __syncthreads();

        // --- dual gate GEMMs: 2-way split accumulators each ---
        f32x4 hacc0 = {}, hacc1 = {}, xacc0 = {}, xacc1 = {};
        #pragma unroll
        for (int kk = 0; kk < 16; kk += 2) {
            bf16x8 hb0 = *(const bf16x8*)(&Hs[lane16][khi * 8 + kk * 32]);
            bf16x8 hb1 = *(const bf16x8*)(&Hs[lane16][khi * 8 + kk * 32 + 32]);
            bf16x8 xb0 = *(const bf16x8*)(&Xh[lane16][khi * 8 + kk * 32]);
            bf16x8 xb1 = *(const bf16x8*)(&Xh[lane16][khi * 8 + kk * 32 + 32]);
            hacc0 = __builtin_amdgcn_mfma_f32_16x16x32_bf16(wreg[kk],      hb0, hacc0, 0, 0, 0);
            hacc1 = __builtin_amdgcn_mfma_f32_16x16x32_bf16(wreg[kk + 1],  hb1, hacc1, 0, 0, 0);
            xacc0 = __builtin_amdgcn_mfma_f32_16x16x32_bf16(wxreg[kk],     xb0, xacc0, 0, 0, 0);
            xacc1 = __builtin_amdgcn_mfma_f32_16x16x32_bf16(wxreg[kk + 1], xb1, xacc1, 0, 0, 0);
        }
        f32x4 hacc = hacc0 + hacc1;
        f32x4 xacc = xacc0 + xacc1;
        float mcol = mds[t * 32 + bt * 16 + lane16];
        #pragma unroll
        for (int r = 0; r < 4; ++r)
            Gs[g][khi * 4 + r][lane16] = xacc[r] + mcol * hacc[r];
        __syncthreads();

        // --- pointwise update ---
        int row = t * 32 + b;
        float m = mds[row];
        float ai = bsv[0] + Gs[0][jloc][bloc];
        float af = bsv[1] + Gs[1][jloc][bloc];
        float ag = bsv[2] + Gs[2][jloc][bloc];
        float ao = bsv[3] + Gs[3][jloc][bloc];
        float cp = c_reg * m;
        float si = 1.f / (1.f + __expf(-ai));
        float sf = 1.f / (1.f + __expf(-af));
        float so = 1.f / (1.f + __expf(-ao));
        c_reg = sf * cp + si * tanhf(ag);
        float hn = so * tanhf(c_reg);
        feat[(size_t)row * 512 + j] = f2bf(hn);
        if (t == 63) {
            hN[b * 512 + j] = hn;
            cN[b * 512 + j] = c_reg;
        }

        // --- grid barrier: release-add, relaxed spin, one acquire fence ---
        if (t < 63) {
            __syncthreads();
            if (tid == 0) {
                int target = (t + 1) * 64;
                __hip_atomic_fetch_add(bar, 1, __ATOMIC_ACQ_REL,
                                       __HIP_MEMORY_SCOPE_AGENT);
                while (__hip_atomic_load(bar, __ATOMIC_RELAXED,
                                         __HIP_MEMORY_SCOPE_AGENT) < target)
                    __builtin_amdgcn_s_sleep(8);
                __builtin_amdgcn_fence(__ATOMIC_ACQUIRE, "agent");
            }
            __syncthreads();
        }
    }
}

// ---------------------------------------------------------------------------
extern "C" void kernel_launch(void* const* d_in, const int* in_sizes, int n_in,
                              void* d_out, int out_size, void* d_ws, size_t ws_size,
                              hipStream_t stream) {
    const float* x    = (const float*)d_in[0];
    const float* done = (const float*)d_in[1];
    const float* h0   = (const float*)d_in[2];
    const float* c0   = (const float*)d_in[3];
    const float* c1w  = (const float*)d_in[4];
    const float* c1b  = (const float*)d_in[5];
    const float* c2w  = (const float*)d_in[6];
    const float* c2b  = (const float*)d_in[7];
    const float* c3w  = (const float*)d_in[8];
    const float* c3b  = (const float*)d_in[9];
    const float* fc1w = (const float*)d_in[10];
    const float* fc1b = (const float*)d_in[11];
    const float* fc2w = (const float*)d_in[12];
    const float* fc2b = (const float*)d_in[13];
    const float* wih  = (const float*)d_in[14];
    const float* whh  = (const float*)d_in[15];
    const float* bih  = (const float*)d_in[16];
    const float* bhh  = (const float*)d_in[17];
    const float* dfw  = (const float*)d_in[18];
    const float* dfb  = (const float*)d_in[19];
    const float* dw   = (const float*)d_in[20];
    const float* db   = (const float*)d_in[21];
    float* out = (float*)d_out;

    const size_t CONV_ELEMS = 57802752;            // 2048*4*84*84
    char* S = (char*)d_ws;
    unsigned short* c3out  = (unsigned short*)S;   S += CONV_ELEMS * 2;
    unsigned short* fc1w_b = (unsigned short*)S;   S += 28901376;
    unsigned short* fc2w_b = (unsigned short*)S;   S += 524288;
    unsigned short* wih_b  = (unsigned short*)S;   S += 2097152;
    unsigned short* whh_b  = (unsigned short*)S;   S += 2097152;
    unsigned short* dfw_b  = (unsigned short*)S;   S += 131072;
    unsigned short* dw_b   = (unsigned short*)S;   S += 16384;
    unsigned short* hfc1_b = (unsigned short*)S;   S += 2097152;
    unsigned short* hfc2_b = (unsigned short*)S;   S += 2097152;
    unsigned short* feat_b = (unsigned short*)S;   S += 2097152;
    unsigned short* dfeat_b= (unsigned short*)S;   S += 524288;
    unsigned short* HA     = (unsigned short*)S;   S += 32768;
    float*          part   = (float*)S;            S += 37748736;  // 9x[2048][512] f32
    int*            bar    = (int*)S;              S += 256;

    // --- fused conv stack (single kernel) ---
    conv_fused_kernel<<<dim3(2048, 6), 256, 0, stream>>>(
        x, c1w, c1b, c2w, c2b, c3w, c3b, c3out);

    // --- weight conversions ---
    auto cvt = [&](const float* s, unsigned short* d, int n) {
        int n4 = n / 4;
        cvt_bf16_kernel<<<(n4 + 255) / 256, 256, 0, stream>>>(s, d, n4);
    };
    cvt(fc1w, fc1w_b, 14450688);
    cvt(fc2w, fc2w_b, 262144);
    cvt(wih,  wih_b,  1048576);
    cvt(whh,  whh_b,  1048576);
    cvt(dfw,  dfw_b,  65536);
    cvt(dw,   dw_b,   8192);

    // --- fc1: split-K x9 (K = 28224 = 9*3136), then reduce+bias+lrelu ---
    gemm_bf16_splitk_kernel<<<dim3(8, 32, 9), 256, 0, stream>>>(
        c3out, fc1w_b, part, 2048, 512, 28224, 3136);
    splitk_reduce_kernel<9><<<dim3(1024), 256, 0, stream>>>(
        part, fc1b, hfc1_b, 1048576, 512);

    // --- fc2 ---
    gemm_bf16_kernel<true, false, true><<<dim3(8, 32), 256, 0, stream>>>(
        hfc1_b, fc2w_b, fc2b, nullptr, hfc2_b, 2048, 512, 512);

    // --- LSTM scan (single persistent launch; x-gate GEMM fused in) ---
    lstm_init_kernel<<<dim3(64), 256, 0, stream>>>(h0, HA, bar);
    lstm_scan_kernel<<<dim3(64), 256, 0, stream>>>(
        whh_b, wih_b, bih, bhh, HA, c0, hfc2_b, done, feat_b,
        out + 131072, out + 131072 + 16384, bar);

    // --- discriminator head ---
    gemm_bf16_kernel<true, false, true><<<dim3(2, 32), 256, 0, stream>>>(
        feat_b, dfw_b, dfb, nullptr, dfeat_b, 2048, 128, 512);
    gemm_bf16_kernel<false, false, false><<<dim3(1, 32), 256, 0, stream>>>(
        dfeat_b, dw_b, db, nullptr, out, 2048, 64, 128);
}